// Round 9
// baseline (40.547 us; speedup 1.0000x reference)
//
#include <hip/hip_runtime.h>
#include <stdint.h>

namespace {

typedef _Float16 half_t;
typedef _Float16 half2_t __attribute__((ext_vector_type(2)));

constexpr int D    = 128;   // feature dim
constexpr int WFm  = 80;    // feature map width
constexpr int HFm  = 60;    // feature map height
constexpr int NPIX = WFm * HFm;
constexpr int NKPT = 1024;
constexpr int LCX  = 12;    // window lattice cols
constexpr int LCY  = 10;    // window lattice rows
constexpr int NLAT = LCX * LCY;

__device__ __forceinline__ float wsum(float v) {
#pragma unroll
  for (int m = 32; m; m >>= 1) v += __shfl_xor(v, m, 64);
  return v;
}
__device__ __forceinline__ float wmax(float v) {
#pragma unroll
  for (int m = 32; m; m >>= 1) v = fmaxf(v, __shfl_xor(v, m, 64));
  return v;
}

__device__ __forceinline__ float dot2acc(uint32_t m, uint32_t f, float acc) {
#if defined(__has_builtin) && __has_builtin(__builtin_amdgcn_fdot2)
  return __builtin_amdgcn_fdot2(__builtin_bit_cast(half2_t, m),
                                __builtin_bit_cast(half2_t, f), acc, false);
#else
  half2_t a = __builtin_bit_cast(half2_t, m);
  half2_t b = __builtin_bit_cast(half2_t, f);
  return acc + (float)a.x * (float)b.x + (float)a.y * (float)b.y;
#endif
}
__device__ __forceinline__ float dot4x2(uint4 m, uint4 f, float acc) {
  acc = dot2acc(m.x, f.x, acc);
  acc = dot2acc(m.y, f.y, acc);
  acc = dot2acc(m.z, f.z, acc);
  acc = dot2acc(m.w, f.w, acc);
  return acc;
}

// ---------------------------------------------------------------------------
// prep: xfH[b][pix][d] = fp16( s[pix] * xf[b][d][pix] )   (pixel-major, = fm)
//       sc[b][pix]     = s[pix] = T / max(||xf[:,pix]||, 1e-12)
// ---------------------------------------------------------------------------
__global__ __launch_bounds__(256) void prep_kernel(
    const float* __restrict__ xf1, const float* __restrict__ xf2,
    const int* __restrict__ epoch,
    half_t* __restrict__ xf1H, half_t* __restrict__ xf2H,
    float* __restrict__ sc1, float* __restrict__ sc2) {
  __shared__ float tile[32 * 129];
  __shared__ float qSh[8][32];
  __shared__ float sSh[32];

  const int bi   = blockIdx.x;          // 0..599
  const int img  = bi / 300;
  const int rem  = bi % 300;
  const int b    = rem / 150;
  const int p0   = (rem % 150) * 32;
  const int tid  = threadIdx.x;

  const float* src  = img ? xf2 : xf1;
  half_t* dstH      = img ? xf2H : xf1H;
  float* dstS       = img ? sc2 : sc1;
  const float T     = fminf(1.0f + (float)(*epoch), 50.0f);

  const int dc = tid >> 5;       // 0..7
  const int px = tid & 31;       // 0..31
#pragma unroll 4
  for (int it = 0; it < 16; ++it) {
    int d = it * 8 + dc;
    tile[px * 129 + d] = src[((size_t)(b * D + d)) * NPIX + p0 + px];
  }
  __syncthreads();

  {
    float s = 0.f;
    const int d0 = dc * 16;
#pragma unroll 8
    for (int d = 0; d < 16; ++d) {
      float v = tile[px * 129 + d0 + d];
      s += v * v;
    }
    qSh[dc][px] = s;
  }
  __syncthreads();
  if (tid < 32) {
    float s = 0.f;
#pragma unroll
    for (int k = 0; k < 8; ++k) s += qSh[k][tid];
    float sv = T / fmaxf(sqrtf(s), 1e-12f);
    dstS[b * NPIX + p0 + tid] = sv;
    sSh[tid] = sv;
  }
  __syncthreads();

#pragma unroll 4
  for (int it = 0; it < 8; ++it) {
    int idx = it * 256 + tid;       // pair index, 0..2047
    int lpx = idx >> 6;             // 0..31
    int dp  = idx & 63;             // 0..63
    float s = sSh[lpx];
    half2_t hv;
    hv.x = (half_t)(tile[lpx * 129 + 2 * dp] * s);
    hv.y = (half_t)(tile[lpx * 129 + 2 * dp + 1] * s);
    *reinterpret_cast<half2_t*>(dstH + ((size_t)(b * NPIX + p0 + lpx)) * D + 2 * dp) = hv;
  }
}

// ---------------------------------------------------------------------------
// main: TWO WAVES per (dir, b, n) — 128-thread block per keypoint, 4096
// blocks. Wave 0 & 1 split phase 2 (64 epi samples each, depth-2 pipeline),
// phase 4 (5 lattice rows each) and phase 5 (128 window samples each).
// Wave 0 does the descriptor while wave 1 fills the line-param table.
// ---------------------------------------------------------------------------
__global__ __launch_bounds__(128) void line2win_kernel(
    const half_t* __restrict__ xf1H, const half_t* __restrict__ xf2H,
    const float* __restrict__ sc1, const float* __restrict__ sc2,
    const float* __restrict__ F1, const float* __restrict__ F2,
    const float* __restrict__ c1n, const float* __restrict__ c2n,
    float* __restrict__ out) {
  __shared__ __align__(16) half_t featH[D];          // 256 B
  __shared__ float4 sPar[2][128];                    // 4 KB
  __shared__ float corrSh[128];                      // 512 B
  __shared__ float dm[NLAT + 8];                     // 512 B
  __shared__ float pT[2][5];                         // 40 B

  const int tid  = threadIdx.x;    // 0..127
  const int lane = tid & 63;
  const int wvh  = tid >> 6;       // 0 or 1
  // XCD-aware decode: wg w -> XCD w%8 (round-robin heuristic); each (dir,b)
  // combo owns one XCD pair so its two maps (~2.4 MB) L2-fit.
  const int w    = blockIdx.x;          // 0..4095
  const int xcd  = w & 7;
  const int comb = xcd >> 1;            // 0..3 = (dir,b)
  const int dir  = comb >> 1;
  const int b    = comb & 1;
  const int n    = (w >> 3) * 2 + (xcd & 1);   // 0..1023
  const int kix  = b * NKPT + n;

  const half_t* srcH = dir ? xf2H : xf1H;  // descriptor source (pre-scaled fm)
  const float*  ssc  = dir ? sc2 : sc1;    // source scale (to undo)
  const half_t* tgtH = dir ? xf1H : xf2H;  // correlation target (pre-scaled fm)
  const float*  Fm   = (dir ? F2 : F1) + b * 9;
  const float*  cn   = (dir ? c2n : c1n) + kix * 2;

  const float cnx_in = cn[0], cny_in = cn[1];
  const float px = (cnx_in + 1.f) * 319.5f;
  const float py = (cny_in + 1.f) * 239.5f;

  const float la = Fm[0] * px + Fm[1] * py + Fm[2];
  const float lb = Fm[3] * px + Fm[4] * py + Fm[5];
  const float lc = Fm[6] * px + Fm[7] * py + Fm[8];
  const float eps = 1e-8f;
  const bool  use_x = fabsf(lb) >= fabsf(la);
  const float bden  = (fabsf(lb) < eps) ? eps : lb;
  const float aden  = (fabsf(la) < eps) ? eps : la;
  const float rdenom = 1.f / (use_x ? bden : aden);
  const bool  degen = (fabsf(la) < eps) && (fabsf(lb) < eps);

  const size_t tb = (size_t)b * NPIX * D;

  if (wvh == 0) {
    // ---- phase 1a (wave 0): descriptor, lane holds d-pair 2*lane,2*lane+1 ----
    float f0 = 0.f, f1 = 0.f;
    {
      float xf = (cnx_in + 1.f) * 39.5f;
      float yf = (cny_in + 1.f) * 29.5f;
      float x0 = floorf(xf), y0 = floorf(yf);
      float wx1 = xf - x0, wx0 = 1.f - wx1;
      float wy1 = yf - y0, wy0 = 1.f - wy1;
#pragma unroll
      for (int cyi = 0; cyi < 2; ++cyi)
#pragma unroll
        for (int cxi = 0; cxi < 2; ++cxi) {
          float xi = x0 + (float)cxi, yi = y0 + (float)cyi;
          bool inb = (xi >= 0.f) && (xi <= (float)(WFm - 1)) &&
                     (yi >= 0.f) && (yi <= (float)(HFm - 1));
          float wgt = (cxi ? wx1 : wx0) * (cyi ? wy1 : wy0);
          if (inb && wgt != 0.f) {
            int p = (int)yi * WFm + (int)xi;
            float coef = wgt / ssc[b * NPIX + p];
            half2_t hv = *reinterpret_cast<const half2_t*>(srcH + tb + (size_t)p * D + 2 * lane);
            f0 += coef * (float)hv.x;
            f1 += coef * (float)hv.y;
          }
        }
    }
    const float nrm = wsum(f0 * f0 + f1 * f1);
    const float inv = 1.f / fmaxf(sqrtf(nrm), 1e-12f);
    half2_t hv;
    hv.x = (half_t)(f0 * inv);
    hv.y = (half_t)(f1 * inv);
    *reinterpret_cast<half2_t*>(&featH[2 * lane]) = hv;
  } else {
    // ---- phase 1b (wave 1): per-sample line params (2 samples/lane) ----
#pragma unroll
    for (int q = 0; q < 2; ++q) {
      int j = lane + q * 64;
      float tpar = (float)j / 127.0f;
      float xs, ys;
      if (use_x) { xs = tpar * 639.f; ys = -fmaf(la, xs, lc) * rdenom; }
      else       { ys = tpar * 479.f; xs = -fmaf(lb, ys, lc) * rdenom; }
      float xff = fminf(fmaxf(xs * (39.5f / 319.5f), -4.f), 84.f);
      float yff = fminf(fmaxf(ys * (29.5f / 239.5f), -4.f), 64.f);
      float x0f = floorf(xff), y0f = floorf(yff);
      int  x0i = (int)x0f, y0i = (int)y0f;
      float wx1 = xff - x0f, wx0 = 1.f - wx1;
      float wy1 = yff - y0f;
      int  xLow = min(max(x0i, 0), WFm - 2);
      float cL0 = (xLow == x0i) ? wx0 : ((xLow == x0i + 1) ? wx1 : 0.f);
      float cH0 = (xLow + 1 == x0i) ? wx0 : ((xLow + 1 == x0i + 1) ? wx1 : 0.f);
#pragma unroll
      for (int h = 0; h < 2; ++h) {
        int yi = y0i + h;
        bool yin = (yi >= 0) && (yi <= HFm - 1);
        int yc = min(max(yi, 0), HFm - 1);
        float wyh = h ? wy1 : (1.f - wy1);
        float ymul = yin ? wyh : 0.f;
        float4 p4;
        p4.x = __int_as_float(yc * WFm + xLow);
        p4.y = cL0 * ymul;
        p4.z = cH0 * ymul;
        p4.w = 0.f;
        sPar[h][j] = p4;
      }
    }
  }
  __syncthreads();

  const uint4* fH4 = reinterpret_cast<const uint4*>(featH);

  // ---- phase 2: epipolar gather — this wave's 16 iters, depth-2 pipeline ----
  {
    const int g = lane >> 4;          // sample slot 0..3
    const int s = lane & 7;
    const int h = (lane >> 3) & 1;
    const uint4 fL0 = fH4[s];
    const uint4 fL1 = fH4[8 + s];
    const int jb = wvh * 64 + g;      // base sample for rt=0

    // stage A: rt 0
    float4 pA = sPar[h][jb];
    bool actA = (pA.y != 0.f) || (pA.z != 0.f);
    uint4 a0{}, a1{}, a2{}, a3{};
    if (actA) {
      const uint4* rp = reinterpret_cast<const uint4*>(
          tgtH + tb + (size_t)__float_as_int(pA.x) * D);
      a0 = rp[s]; a1 = rp[8 + s]; a2 = rp[16 + s]; a3 = rp[24 + s];
    }
    // stage B: rt 1
    float4 pB = sPar[h][jb + 4];
    bool actB = (pB.y != 0.f) || (pB.z != 0.f);
    uint4 b0{}, b1{}, b2{}, b3{};
    if (actB) {
      const uint4* rp = reinterpret_cast<const uint4*>(
          tgtH + tb + (size_t)__float_as_int(pB.x) * D);
      b0 = rp[s]; b1 = rp[8 + s]; b2 = rp[16 + s]; b3 = rp[24 + s];
    }

#pragma unroll
    for (int rt = 0; rt < 16; ++rt) {
      // prefetch stage C: rt+2
      float4 pC = {0.f, 0.f, 0.f, 0.f};
      bool actC = false;
      uint4 c0{}, c1{}, c2{}, c3{};
      if (rt < 14) {
        pC = sPar[h][jb + (rt + 2) * 4];
        actC = (pC.y != 0.f) || (pC.z != 0.f);
        if (actC) {
          const uint4* rp = reinterpret_cast<const uint4*>(
              tgtH + tb + (size_t)__float_as_int(pC.x) * D);
          c0 = rp[s]; c1 = rp[8 + s]; c2 = rp[16 + s]; c3 = rp[24 + s];
        }
      }
      // compute stage A
      float acc = 0.f;
      if (actA) {
        float accL = dot4x2(a1, fL1, dot4x2(a0, fL0, 0.f));
        float accH = dot4x2(a3, fL1, dot4x2(a2, fL0, 0.f));
        acc = pA.y * accL + pA.z * accH;
      }
      acc += __shfl_xor(acc, 1, 64);
      acc += __shfl_xor(acc, 2, 64);
      acc += __shfl_xor(acc, 4, 64);
      acc += __shfl_xor(acc, 8, 64);   // merge y-halves
      if ((lane & 15) == 0) corrSh[jb + rt * 4] = acc;
      // rotate stages
      pA = pB; actA = actB; a0 = b0; a1 = b1; a2 = b2; a3 = b3;
      pB = pC; actB = actC; b0 = c0; b1 = c1; b2 = c2; b3 = c3;
    }
  }
  __syncthreads();

  // ---- phase 3: masked softmax over L=128 (redundant per wave) ----
  float e0, e1, cx0, cy0, cx1, cy1;
  bool v0, v1;
  {
    float lgt0, lgt1;
#pragma unroll
    for (int q = 0; q < 2; ++q) {
      int j = lane + q * 64;
      float tpar = (float)j / 127.0f;
      float xs, ys;
      if (use_x) { xs = tpar * 639.f; ys = -fmaf(la, xs, lc) * rdenom; }
      else       { ys = tpar * 479.f; xs = -fmaf(lb, ys, lc) * rdenom; }
      bool valid = (xs >= 0.f) && (xs <= 639.f) && (ys >= 0.f) && (ys <= 479.f) && !degen;
      float cxj = xs / 319.5f - 1.f;
      float cyj = ys / 239.5f - 1.f;
      float lg = valid ? corrSh[j] : -1e9f;
      if (q == 0) { v0 = valid; cx0 = cxj; cy0 = cyj; lgt0 = lg; }
      else        { v1 = valid; cx1 = cxj; cy1 = cyj; lgt1 = lg; }
    }
    const float mx = wmax(fmaxf(lgt0, lgt1));
    e0 = expf(lgt0 - mx);
    e1 = expf(lgt1 - mx);
  }
  const float sumE = wsum(e0 + e1);
  const float sumX = wsum(e0 * cx0 + e1 * cx1);
  const float sumY = wsum(e0 * cy0 + e1 * cy1);
  const bool  anyv = __ballot(v0 || v1) != 0ull;
  const float meanx = sumX / sumE;
  const float meany = sumY / sumE;
  const float ccx = fminf(fmaxf(meanx, -0.875f), 0.875f);
  const float ccy = fminf(fmaxf(meany, -0.875f), 0.875f);

  if (tid == 0) {
    float* o_coord = out + dir * 4096 + kix * 2;
    o_coord[0] = px;
    o_coord[1] = py;
    float* o_org = out + 16384 + dir * 4096 + kix * 2;
    if (dir == 0) {
      o_org[0] = (meanx + 1.f) * 319.5f;
      o_org[1] = (meany + 1.f) * 239.5f;
    } else {
      o_org[0] = meanx;
      o_org[1] = meany;
    }
    out[28672 + dir * 2048 + kix] = anyv ? 1.f : 0.f;
  }

  // ---- phase 4: window dot-map — this wave's 5 rows, row-pipelined ----
  const float xfc2 = (ccx + 1.f) * 39.5f;
  const float yfc2 = (ccy + 1.f) * 29.5f;
  const int xb = (int)floorf(xfc2 - 4.9375f);   // >= 0
  const int yb = (int)floorf(yfc2 - 3.6875f);   // >= 0
  {
    const int s4 = lane & 15;
    const int pp = lane >> 4;
    const uint4 fw = fH4[s4];
    // row-invariant clamped x offsets and validity
    const int x0p = xb + pp, x1p = xb + 4 + pp, x2p = xb + 8 + pp;
    const bool okx0 = x0p <= WFm - 1, okx1 = x1p <= WFm - 1, okx2 = x2p <= WFm - 1;
    const int pc0 = min(x0p, WFm - 1) - xb;
    const int pc1 = min(x1p, WFm - 1) - xb;
    const int pc2 = min(x2p, WFm - 1) - xb;

    const uint4* rpA = reinterpret_cast<const uint4*>(
        tgtH + tb + (size_t)(min(yb + wvh, HFm - 1) * WFm + xb) * D);
    uint4 A0 = rpA[pc0 * 16 + s4];
    uint4 A1 = rpA[pc1 * 16 + s4];
    uint4 A2 = rpA[pc2 * 16 + s4];
#pragma unroll
    for (int r8 = 0; r8 < 5; ++r8) {
      const int row = wvh + 2 * r8;     // 0,2,..,8 or 1,3,..,9
      uint4 B0{}, B1{}, B2{};
      if (r8 < 4) {
        int ycl = min(yb + row + 2, HFm - 1);
        const uint4* rpB = reinterpret_cast<const uint4*>(
            tgtH + tb + (size_t)(ycl * WFm + xb) * D);
        B0 = rpB[pc0 * 16 + s4];
        B1 = rpB[pc1 * 16 + s4];
        B2 = rpB[pc2 * 16 + s4];
      }
      bool yok = (yb + row) <= HFm - 1;
      float d0 = dot4x2(A0, fw, 0.f);
      float d1 = dot4x2(A1, fw, 0.f);
      float d2 = dot4x2(A2, fw, 0.f);
#pragma unroll
      for (int m = 1; m <= 8; m <<= 1) {
        d0 += __shfl_xor(d0, m, 64);
        d1 += __shfl_xor(d1, m, 64);
        d2 += __shfl_xor(d2, m, 64);
      }
      if (s4 == 0) {
        dm[row * LCX + pp]     = (yok && okx0) ? d0 : 0.f;
        dm[row * LCX + 4 + pp] = (yok && okx1) ? d1 : 0.f;
        dm[row * LCX + 8 + pp] = (yok && okx2) ? d2 : 0.f;
      }
      A0 = B0; A1 = B1; A2 = B2;
    }
  }
  __syncthreads();

  // ---- phase 5: 256 window samples — 128 per wave, LDS combine ----
  const float step = 0.25f / 15.f;
  float t0 = 0.f, t1 = 0.f, t2 = 0.f, t3 = 0.f, t4 = 0.f;
#pragma unroll
  for (int qq = 0; qq < 2; ++qq) {
    int k = lane + (wvh * 2 + qq) * 64;
    float ox = -0.125f + step * (float)(k & 15);
    float oy = -0.125f + step * (float)(k >> 4);
    float kcx = ccx + ox;
    float kcy = ccy + oy;
    float xfw = xfc2 + ox * 39.5f;
    float yfw = yfc2 + oy * 29.5f;
    float xw0 = floorf(xfw), yw0 = floorf(yfw);
    int ix = (int)xw0 - xb;
    int iy = (int)yw0 - yb;
    float wxx1 = xfw - xw0, wxx0 = 1.f - wxx1;
    float wyy1 = yfw - yw0, wyy0 = 1.f - wyy1;
    int i00 = iy * LCX + ix;
    float c00 = dm[i00], c10 = dm[i00 + 1];
    float c01 = dm[i00 + LCX], c11 = dm[i00 + LCX + 1];
    float corr2 = wxx0 * wyy0 * c00 + wxx1 * wyy0 * c10 +
                  wxx0 * wyy1 * c01 + wxx1 * wyy1 * c11;
    // softmax shift-invariant; logits <= T <= 50 -> expf finite in f32.
    float e2 = expf(corr2);
    t0 += e2;
    t1 += e2 * kcx;
    t2 += e2 * kcy;
    t3 += e2 * kcx * kcx;
    t4 += e2 * kcy * kcy;
  }
  t0 = wsum(t0);
  t1 = wsum(t1);
  t2 = wsum(t2);
  t3 = wsum(t3);
  t4 = wsum(t4);
  if (lane == 0) {
    pT[wvh][0] = t0; pT[wvh][1] = t1; pT[wvh][2] = t2;
    pT[wvh][3] = t3; pT[wvh][4] = t4;
  }
  __syncthreads();
  if (tid == 0) {
    float s0 = pT[0][0] + pT[1][0];
    float s1 = pT[0][1] + pT[1][1];
    float s2 = pT[0][2] + pT[1][2];
    float s3 = pT[0][3] + pT[1][3];
    float s4 = pT[0][4] + pT[1][4];
    float mwx = s1 / s0;
    float mwy = s2 / s0;
    float vx  = fmaxf(s3 / s0 - mwx * mwx, 0.f);
    float vy  = fmaxf(s4 / s0 - mwy * mwy, 0.f);
    float stdv = sqrtf(vx + vy + 1e-12f);
    float* o_w = out + 8192 + dir * 4096 + kix * 2;
    o_w[0] = (mwx + 1.f) * 319.5f;
    o_w[1] = (mwy + 1.f) * 239.5f;
    out[24576 + dir * 2048 + kix] = stdv;
  }
}

}  // namespace

extern "C" void kernel_launch(void* const* d_in, const int* in_sizes, int n_in,
                              void* d_out, int out_size, void* d_ws, size_t ws_size,
                              hipStream_t stream) {
  (void)in_sizes; (void)n_in; (void)out_size; (void)ws_size;
  const float* xf1 = (const float*)d_in[0];
  const float* xf2 = (const float*)d_in[1];
  const float* F1  = (const float*)d_in[2];
  const float* F2  = (const float*)d_in[3];
  const float* c1n = (const float*)d_in[4];
  const float* c2n = (const float*)d_in[5];
  const int* epoch = (const int*)d_in[6];

  half_t* xf1H = (half_t*)d_ws;                           // 2*4800*128 halves
  half_t* xf2H = xf1H + (size_t)2 * NPIX * D;             // 2*4800*128 halves
  float*  sc1  = (float*)(xf2H + (size_t)2 * NPIX * D);   // 2*4800 f32
  float*  sc2  = sc1 + 2 * NPIX;                          // 2*4800 f32
  float*  out  = (float*)d_out;

  hipLaunchKernelGGL(prep_kernel, dim3(600), dim3(256), 0, stream,
                     xf1, xf2, epoch, xf1H, xf2H, sc1, sc2);
  hipLaunchKernelGGL(line2win_kernel, dim3(4096), dim3(128), 0, stream,
                     xf1H, xf2H, sc1, sc2, F1, F2, c1n, c2n, out);
}

// Round 10
// 37.306 us; speedup vs baseline: 1.0869x; 1.0869x over previous
//
#include <hip/hip_runtime.h>
#include <stdint.h>

namespace {

typedef _Float16 half_t;
typedef _Float16 half2_t __attribute__((ext_vector_type(2)));

constexpr int D    = 128;   // feature dim
constexpr int WFm  = 80;    // feature map width
constexpr int HFm  = 60;    // feature map height
constexpr int NPIX = WFm * HFm;
constexpr int NKPT = 1024;
constexpr int LCX  = 12;    // window lattice cols
constexpr int LCY  = 10;    // window lattice rows
constexpr int NLAT = LCX * LCY;

__device__ __forceinline__ float wsum(float v) {
#pragma unroll
  for (int m = 32; m; m >>= 1) v += __shfl_xor(v, m, 64);
  return v;
}
__device__ __forceinline__ float wmax(float v) {
#pragma unroll
  for (int m = 32; m; m >>= 1) v = fmaxf(v, __shfl_xor(v, m, 64));
  return v;
}

__device__ __forceinline__ float dot2acc(uint32_t m, uint32_t f, float acc) {
#if defined(__has_builtin) && __has_builtin(__builtin_amdgcn_fdot2)
  return __builtin_amdgcn_fdot2(__builtin_bit_cast(half2_t, m),
                                __builtin_bit_cast(half2_t, f), acc, false);
#else
  half2_t a = __builtin_bit_cast(half2_t, m);
  half2_t b = __builtin_bit_cast(half2_t, f);
  return acc + (float)a.x * (float)b.x + (float)a.y * (float)b.y;
#endif
}
__device__ __forceinline__ float dot4x2(uint4 m, uint4 f, float acc) {
  acc = dot2acc(m.x, f.x, acc);
  acc = dot2acc(m.y, f.y, acc);
  acc = dot2acc(m.z, f.z, acc);
  acc = dot2acc(m.w, f.w, acc);
  return acc;
}

// ---------------------------------------------------------------------------
// prep: xfH[b][pix][d] = fp16( s[pix] * xf[b][d][pix] )   (pixel-major, = fm)
//       sc[b][pix]     = s[pix] = T / max(||xf[:,pix]||, 1e-12)
// 32 px/block, 600 blocks; float2 loads + 8B packed stores.
// ---------------------------------------------------------------------------
__global__ __launch_bounds__(256) void prep_kernel(
    const float* __restrict__ xf1, const float* __restrict__ xf2,
    const int* __restrict__ epoch,
    half_t* __restrict__ xf1H, half_t* __restrict__ xf2H,
    float* __restrict__ sc1, float* __restrict__ sc2) {
  __shared__ float tile[32][130];
  __shared__ float qSh[8][32];
  __shared__ float sSh[32];

  const int bi   = blockIdx.x;          // 0..599
  const int img  = bi / 300;
  const int rem  = bi % 300;
  const int b    = rem / 150;
  const int p0   = (rem % 150) * 32;
  const int tid  = threadIdx.x;

  const float* src  = img ? xf2 : xf1;
  half_t* dstH      = img ? xf2H : xf1H;
  float* dstS       = img ? sc2 : sc1;
  const float T     = fminf(1.0f + (float)(*epoch), 50.0f);

  // loads: d-group dc = tid>>4 (16 d rows/iter), pixel-pair pxp = tid&15
  const int dc  = tid >> 4;
  const int pxp = tid & 15;
#pragma unroll
  for (int it = 0; it < 8; ++it) {
    int d = it * 16 + dc;
    float2 v = *reinterpret_cast<const float2*>(
        &src[((size_t)(b * D + d)) * NPIX + p0 + 2 * pxp]);
    tile[2 * pxp][d]     = v.x;
    tile[2 * pxp + 1][d] = v.y;
  }
  __syncthreads();

  {
    const int px = tid & 31;
    const int dg = tid >> 5;
    float s = 0.f;
#pragma unroll
    for (int d = 0; d < 16; ++d) {
      float v = tile[px][dg * 16 + d];
      s += v * v;
    }
    qSh[dg][px] = s;
  }
  __syncthreads();
  if (tid < 32) {
    float s = 0.f;
#pragma unroll
    for (int k = 0; k < 8; ++k) s += qSh[k][tid];
    float sv = T / fmaxf(sqrtf(s), 1e-12f);
    dstS[b * NPIX + p0 + tid] = sv;
    sSh[tid] = sv;
  }
  __syncthreads();

#pragma unroll
  for (int it = 0; it < 4; ++it) {
    int idx = it * 256 + tid;       // quad index, 0..1023
    int lpx = idx >> 5;             // 0..31
    int dq  = (idx & 31) * 4;       // 0..124
    float s = sSh[lpx];
    half2_t h0, h1;
    h0.x = (half_t)(tile[lpx][dq] * s);
    h0.y = (half_t)(tile[lpx][dq + 1] * s);
    h1.x = (half_t)(tile[lpx][dq + 2] * s);
    h1.y = (half_t)(tile[lpx][dq + 3] * s);
    uint2 pack;
    pack.x = __builtin_bit_cast(uint32_t, h0);
    pack.y = __builtin_bit_cast(uint32_t, h1);
    *reinterpret_cast<uint2*>(dstH + ((size_t)(b * NPIX + p0 + lpx)) * D + dq) = pack;
  }
}

// ---------------------------------------------------------------------------
// main: ONE WAVE per (dir, b, n) — 64-thread block, 4096 blocks. Zero
// barriers; R8 phase structure (depth-2 pipelined epi gather, row-pipelined
// window dot-map). Per-block (= per-wave) LDS.
// ---------------------------------------------------------------------------
__global__ __launch_bounds__(64) void line2win_kernel(
    const half_t* __restrict__ xf1H, const half_t* __restrict__ xf2H,
    const float* __restrict__ sc1, const float* __restrict__ sc2,
    const float* __restrict__ F1, const float* __restrict__ F2,
    const float* __restrict__ c1n, const float* __restrict__ c2n,
    float* __restrict__ out) {
  __shared__ __align__(16) half_t featH[D];          // 256 B
  __shared__ float4 sPar[2][128];                    // 4 KB
  __shared__ float corrSh[128];                      // 512 B
  __shared__ float dm[NLAT + 8];                     // 512 B

  const int lane = threadIdx.x;    // 0..63
  // XCD-aware decode: wg w -> XCD w%8 (round-robin heuristic); each (dir,b)
  // combo owns one XCD pair so its two maps (~2.4 MB) L2-fit.
  const int w    = blockIdx.x;          // 0..4095
  const int xcd  = w & 7;
  const int comb = xcd >> 1;            // 0..3 = (dir,b)
  const int dir  = comb >> 1;
  const int b    = comb & 1;
  const int n    = (w >> 3) * 2 + (xcd & 1);   // 0..1023
  const int kix  = b * NKPT + n;

  const half_t* srcH = dir ? xf2H : xf1H;  // descriptor source (pre-scaled fm)
  const float*  ssc  = dir ? sc2 : sc1;    // source scale (to undo)
  const half_t* tgtH = dir ? xf1H : xf2H;  // correlation target (pre-scaled fm)
  const float*  Fm   = (dir ? F2 : F1) + b * 9;
  const float*  cn   = (dir ? c2n : c1n) + kix * 2;

  const float cnx_in = cn[0], cny_in = cn[1];
  const float px = (cnx_in + 1.f) * 319.5f;
  const float py = (cny_in + 1.f) * 239.5f;

  const float la = Fm[0] * px + Fm[1] * py + Fm[2];
  const float lb = Fm[3] * px + Fm[4] * py + Fm[5];
  const float lc = Fm[6] * px + Fm[7] * py + Fm[8];
  const float eps = 1e-8f;
  const bool  use_x = fabsf(lb) >= fabsf(la);
  const float bden  = (fabsf(lb) < eps) ? eps : lb;
  const float aden  = (fabsf(la) < eps) ? eps : la;
  const float rdenom = 1.f / (use_x ? bden : aden);
  const bool  degen = (fabsf(la) < eps) && (fabsf(lb) < eps);

  const size_t tb = (size_t)b * NPIX * D;

  // ---- phase 1a: descriptor (lane holds d-pair 2*lane, 2*lane+1) ----
  float f0 = 0.f, f1 = 0.f;
  {
    float xf = (cnx_in + 1.f) * 39.5f;
    float yf = (cny_in + 1.f) * 29.5f;
    float x0 = floorf(xf), y0 = floorf(yf);
    float wx1 = xf - x0, wx0 = 1.f - wx1;
    float wy1 = yf - y0, wy0 = 1.f - wy1;
#pragma unroll
    for (int cyi = 0; cyi < 2; ++cyi)
#pragma unroll
      for (int cxi = 0; cxi < 2; ++cxi) {
        float xi = x0 + (float)cxi, yi = y0 + (float)cyi;
        bool inb = (xi >= 0.f) && (xi <= (float)(WFm - 1)) &&
                   (yi >= 0.f) && (yi <= (float)(HFm - 1));
        float wgt = (cxi ? wx1 : wx0) * (cyi ? wy1 : wy0);
        if (inb && wgt != 0.f) {
          int p = (int)yi * WFm + (int)xi;
          float coef = wgt / ssc[b * NPIX + p];
          half2_t hv = *reinterpret_cast<const half2_t*>(srcH + tb + (size_t)p * D + 2 * lane);
          f0 += coef * (float)hv.x;
          f1 += coef * (float)hv.y;
        }
      }
  }

  // ---- phase 1b: per-sample line params (lane -> samples lane, lane+64) ----
#pragma unroll
  for (int q = 0; q < 2; ++q) {
    int j = lane + q * 64;
    float tpar = (float)j / 127.0f;
    float xs, ys;
    if (use_x) { xs = tpar * 639.f; ys = -fmaf(la, xs, lc) * rdenom; }
    else       { ys = tpar * 479.f; xs = -fmaf(lb, ys, lc) * rdenom; }
    float xff = fminf(fmaxf(xs * (39.5f / 319.5f), -4.f), 84.f);
    float yff = fminf(fmaxf(ys * (29.5f / 239.5f), -4.f), 64.f);
    float x0f = floorf(xff), y0f = floorf(yff);
    int  x0i = (int)x0f, y0i = (int)y0f;
    float wx1 = xff - x0f, wx0 = 1.f - wx1;
    float wy1 = yff - y0f;
    int  xLow = min(max(x0i, 0), WFm - 2);
    float cL0 = (xLow == x0i) ? wx0 : ((xLow == x0i + 1) ? wx1 : 0.f);
    float cH0 = (xLow + 1 == x0i) ? wx0 : ((xLow + 1 == x0i + 1) ? wx1 : 0.f);
#pragma unroll
    for (int h = 0; h < 2; ++h) {
      int yi = y0i + h;
      bool yin = (yi >= 0) && (yi <= HFm - 1);
      int yc = min(max(yi, 0), HFm - 1);
      float wyh = h ? wy1 : (1.f - wy1);
      float ymul = yin ? wyh : 0.f;
      float4 p4;
      p4.x = __int_as_float(yc * WFm + xLow);
      p4.y = cL0 * ymul;
      p4.z = cH0 * ymul;
      p4.w = 0.f;
      sPar[h][j] = p4;
    }
  }

  // ---- phase 1c: norm (butterfly -> all lanes) + feature store ----
  const float nrm = wsum(f0 * f0 + f1 * f1);
  const float inv = 1.f / fmaxf(sqrtf(nrm), 1e-12f);
  {
    half2_t hv;
    hv.x = (half_t)(f0 * inv);
    hv.y = (half_t)(f1 * inv);
    *reinterpret_cast<half2_t*>(&featH[2 * lane]) = hv;
  }

  const uint4* fH4 = reinterpret_cast<const uint4*>(featH);

  // ---- phase 2: epipolar gather — 16 lanes/sample, depth-2 pipeline ----
  {
    const int g = lane >> 4;          // sample slot 0..3 (j = it*4+g)
    const int s = lane & 7;
    const int h = (lane >> 3) & 1;
    const uint4 fL0 = fH4[s];
    const uint4 fL1 = fH4[8 + s];

    // stage A: iter 0
    float4 pA = sPar[h][g];
    bool actA = (pA.y != 0.f) || (pA.z != 0.f);
    uint4 a0{}, a1{}, a2{}, a3{};
    if (actA) {
      const uint4* rp = reinterpret_cast<const uint4*>(
          tgtH + tb + (size_t)__float_as_int(pA.x) * D);
      a0 = rp[s]; a1 = rp[8 + s]; a2 = rp[16 + s]; a3 = rp[24 + s];
    }
    // stage B: iter 1
    float4 pB = sPar[h][4 + g];
    bool actB = (pB.y != 0.f) || (pB.z != 0.f);
    uint4 b0{}, b1{}, b2{}, b3{};
    if (actB) {
      const uint4* rp = reinterpret_cast<const uint4*>(
          tgtH + tb + (size_t)__float_as_int(pB.x) * D);
      b0 = rp[s]; b1 = rp[8 + s]; b2 = rp[16 + s]; b3 = rp[24 + s];
    }

#pragma unroll
    for (int it = 0; it < 32; ++it) {
      // prefetch stage C: iter it+2
      float4 pC = {0.f, 0.f, 0.f, 0.f};
      bool actC = false;
      uint4 c0{}, c1{}, c2{}, c3{};
      if (it < 30) {
        pC = sPar[h][(it + 2) * 4 + g];
        actC = (pC.y != 0.f) || (pC.z != 0.f);
        if (actC) {
          const uint4* rp = reinterpret_cast<const uint4*>(
              tgtH + tb + (size_t)__float_as_int(pC.x) * D);
          c0 = rp[s]; c1 = rp[8 + s]; c2 = rp[16 + s]; c3 = rp[24 + s];
        }
      }
      // compute stage A
      float acc = 0.f;
      if (actA) {
        float accL = dot4x2(a1, fL1, dot4x2(a0, fL0, 0.f));
        float accH = dot4x2(a3, fL1, dot4x2(a2, fL0, 0.f));
        acc = pA.y * accL + pA.z * accH;
      }
      acc += __shfl_xor(acc, 1, 64);
      acc += __shfl_xor(acc, 2, 64);
      acc += __shfl_xor(acc, 4, 64);
      acc += __shfl_xor(acc, 8, 64);   // merge y-halves
      if ((lane & 15) == 0) corrSh[it * 4 + g] = acc;
      // rotate stages
      pA = pB; actA = actB; a0 = b0; a1 = b1; a2 = b2; a3 = b3;
      pB = pC; actB = actC; b0 = c0; b1 = c1; b2 = c2; b3 = c3;
    }
  }

  // ---- phase 3: masked softmax over L=128 (2 samples/lane, butterflies) ----
  float e0, e1, cx0, cy0, cx1, cy1;
  bool v0, v1;
  {
    float lgt0, lgt1;
#pragma unroll
    for (int q = 0; q < 2; ++q) {
      int j = lane + q * 64;
      float tpar = (float)j / 127.0f;
      float xs, ys;
      if (use_x) { xs = tpar * 639.f; ys = -fmaf(la, xs, lc) * rdenom; }
      else       { ys = tpar * 479.f; xs = -fmaf(lb, ys, lc) * rdenom; }
      bool valid = (xs >= 0.f) && (xs <= 639.f) && (ys >= 0.f) && (ys <= 479.f) && !degen;
      float cxj = xs / 319.5f - 1.f;
      float cyj = ys / 239.5f - 1.f;
      float lg = valid ? corrSh[j] : -1e9f;
      if (q == 0) { v0 = valid; cx0 = cxj; cy0 = cyj; lgt0 = lg; }
      else        { v1 = valid; cx1 = cxj; cy1 = cyj; lgt1 = lg; }
    }
    const float mx = wmax(fmaxf(lgt0, lgt1));
    e0 = expf(lgt0 - mx);
    e1 = expf(lgt1 - mx);
  }
  const float sumE = wsum(e0 + e1);
  const float sumX = wsum(e0 * cx0 + e1 * cx1);
  const float sumY = wsum(e0 * cy0 + e1 * cy1);
  const bool  anyv = __ballot(v0 || v1) != 0ull;
  const float meanx = sumX / sumE;
  const float meany = sumY / sumE;
  const float ccx = fminf(fmaxf(meanx, -0.875f), 0.875f);
  const float ccy = fminf(fmaxf(meany, -0.875f), 0.875f);

  if (lane == 0) {
    float* o_coord = out + dir * 4096 + kix * 2;
    o_coord[0] = px;
    o_coord[1] = py;
    float* o_org = out + 16384 + dir * 4096 + kix * 2;
    if (dir == 0) {
      o_org[0] = (meanx + 1.f) * 319.5f;
      o_org[1] = (meany + 1.f) * 239.5f;
    } else {
      o_org[0] = meanx;
      o_org[1] = meany;
    }
    out[28672 + dir * 2048 + kix] = anyv ? 1.f : 0.f;
  }

  // ---- phase 4: window dot-map, 16 lanes/pixel, row-pipelined loads ----
  const float xfc2 = (ccx + 1.f) * 39.5f;
  const float yfc2 = (ccy + 1.f) * 29.5f;
  const int xb = (int)floorf(xfc2 - 4.9375f);   // >= 0
  const int yb = (int)floorf(yfc2 - 3.6875f);   // >= 0
  {
    const int s4 = lane & 15;
    const int pp = lane >> 4;
    const uint4 fw = fH4[s4];
    // row-invariant clamped x offsets and validity
    const int x0p = xb + pp, x1p = xb + 4 + pp, x2p = xb + 8 + pp;
    const bool okx0 = x0p <= WFm - 1, okx1 = x1p <= WFm - 1, okx2 = x2p <= WFm - 1;
    const int pc0 = min(x0p, WFm - 1) - xb;
    const int pc1 = min(x1p, WFm - 1) - xb;
    const int pc2 = min(x2p, WFm - 1) - xb;

    const uint4* rpA = reinterpret_cast<const uint4*>(
        tgtH + tb + (size_t)(min(yb, HFm - 1) * WFm + xb) * D);
    uint4 A0 = rpA[pc0 * 16 + s4];
    uint4 A1 = rpA[pc1 * 16 + s4];
    uint4 A2 = rpA[pc2 * 16 + s4];
#pragma unroll
    for (int row = 0; row < LCY; ++row) {
      uint4 B0{}, B1{}, B2{};
      if (row < LCY - 1) {
        int ycl = min(yb + row + 1, HFm - 1);
        const uint4* rpB = reinterpret_cast<const uint4*>(
            tgtH + tb + (size_t)(ycl * WFm + xb) * D);
        B0 = rpB[pc0 * 16 + s4];
        B1 = rpB[pc1 * 16 + s4];
        B2 = rpB[pc2 * 16 + s4];
      }
      bool yok = (yb + row) <= HFm - 1;
      float d0 = dot4x2(A0, fw, 0.f);
      float d1 = dot4x2(A1, fw, 0.f);
      float d2 = dot4x2(A2, fw, 0.f);
#pragma unroll
      for (int m = 1; m <= 8; m <<= 1) {
        d0 += __shfl_xor(d0, m, 64);
        d1 += __shfl_xor(d1, m, 64);
        d2 += __shfl_xor(d2, m, 64);
      }
      if (s4 == 0) {
        dm[row * LCX + pp]     = (yok && okx0) ? d0 : 0.f;
        dm[row * LCX + 4 + pp] = (yok && okx1) ? d1 : 0.f;
        dm[row * LCX + 8 + pp] = (yok && okx2) ? d2 : 0.f;
      }
      A0 = B0; A1 = B1; A2 = B2;
    }
  }

  // ---- phase 5: 256 window samples (4/lane), softmax + mean + std ----
  const float step = 0.25f / 15.f;
  float t0 = 0.f, t1 = 0.f, t2 = 0.f, t3 = 0.f, t4 = 0.f;
#pragma unroll
  for (int q = 0; q < 4; ++q) {
    int k = lane + q * 64;
    float ox = -0.125f + step * (float)(k & 15);
    float oy = -0.125f + step * (float)(k >> 4);
    float kcx = ccx + ox;
    float kcy = ccy + oy;
    float xfw = xfc2 + ox * 39.5f;
    float yfw = yfc2 + oy * 29.5f;
    float xw0 = floorf(xfw), yw0 = floorf(yfw);
    int ix = (int)xw0 - xb;
    int iy = (int)yw0 - yb;
    float wxx1 = xfw - xw0, wxx0 = 1.f - wxx1;
    float wyy1 = yfw - yw0, wyy0 = 1.f - wyy1;
    int i00 = iy * LCX + ix;
    float c00 = dm[i00], c10 = dm[i00 + 1];
    float c01 = dm[i00 + LCX], c11 = dm[i00 + LCX + 1];
    float corr2 = wxx0 * wyy0 * c00 + wxx1 * wyy0 * c10 +
                  wxx0 * wyy1 * c01 + wxx1 * wyy1 * c11;
    // softmax shift-invariant; logits <= T <= 50 -> expf finite in f32.
    float e2 = expf(corr2);
    t0 += e2;
    t1 += e2 * kcx;
    t2 += e2 * kcy;
    t3 += e2 * kcx * kcx;
    t4 += e2 * kcy * kcy;
  }
  t0 = wsum(t0);
  t1 = wsum(t1);
  t2 = wsum(t2);
  t3 = wsum(t3);
  t4 = wsum(t4);
  if (lane == 0) {
    float mwx = t1 / t0;
    float mwy = t2 / t0;
    float vx  = fmaxf(t3 / t0 - mwx * mwx, 0.f);
    float vy  = fmaxf(t4 / t0 - mwy * mwy, 0.f);
    float stdv = sqrtf(vx + vy + 1e-12f);
    float* o_w = out + 8192 + dir * 4096 + kix * 2;
    o_w[0] = (mwx + 1.f) * 319.5f;
    o_w[1] = (mwy + 1.f) * 239.5f;
    out[24576 + dir * 2048 + kix] = stdv;
  }
}

}  // namespace

extern "C" void kernel_launch(void* const* d_in, const int* in_sizes, int n_in,
                              void* d_out, int out_size, void* d_ws, size_t ws_size,
                              hipStream_t stream) {
  (void)in_sizes; (void)n_in; (void)out_size; (void)ws_size;
  const float* xf1 = (const float*)d_in[0];
  const float* xf2 = (const float*)d_in[1];
  const float* F1  = (const float*)d_in[2];
  const float* F2  = (const float*)d_in[3];
  const float* c1n = (const float*)d_in[4];
  const float* c2n = (const float*)d_in[5];
  const int* epoch = (const int*)d_in[6];

  half_t* xf1H = (half_t*)d_ws;                           // 2*4800*128 halves
  half_t* xf2H = xf1H + (size_t)2 * NPIX * D;             // 2*4800*128 halves
  float*  sc1  = (float*)(xf2H + (size_t)2 * NPIX * D);   // 2*4800 f32
  float*  sc2  = sc1 + 2 * NPIX;                          // 2*4800 f32
  float*  out  = (float*)d_out;

  hipLaunchKernelGGL(prep_kernel, dim3(600), dim3(256), 0, stream,
                     xf1, xf2, epoch, xf1H, xf2H, sc1, sc2);
  hipLaunchKernelGGL(line2win_kernel, dim3(4096), dim3(64), 0, stream,
                     xf1H, xf2H, sc1, sc2, F1, F2, c1n, c2n, out);
}

// Round 11
// 36.838 us; speedup vs baseline: 1.1007x; 1.0127x over previous
//
#include <hip/hip_runtime.h>
#include <stdint.h>

namespace {

typedef _Float16 half_t;
typedef _Float16 half2_t __attribute__((ext_vector_type(2)));

constexpr int D    = 128;   // feature dim
constexpr int WFm  = 80;    // feature map width
constexpr int HFm  = 60;    // feature map height
constexpr int NPIX = WFm * HFm;
constexpr int NKPT = 1024;
constexpr int LCX  = 12;    // window lattice cols
constexpr int LCY  = 10;    // window lattice rows
constexpr int NLAT = LCX * LCY;

__device__ __forceinline__ float wsum(float v) {
#pragma unroll
  for (int m = 32; m; m >>= 1) v += __shfl_xor(v, m, 64);
  return v;
}
__device__ __forceinline__ float wmax(float v) {
#pragma unroll
  for (int m = 32; m; m >>= 1) v = fmaxf(v, __shfl_xor(v, m, 64));
  return v;
}

__device__ __forceinline__ float dot2acc(uint32_t m, uint32_t f, float acc) {
#if defined(__has_builtin) && __has_builtin(__builtin_amdgcn_fdot2)
  return __builtin_amdgcn_fdot2(__builtin_bit_cast(half2_t, m),
                                __builtin_bit_cast(half2_t, f), acc, false);
#else
  half2_t a = __builtin_bit_cast(half2_t, m);
  half2_t b = __builtin_bit_cast(half2_t, f);
  return acc + (float)a.x * (float)b.x + (float)a.y * (float)b.y;
#endif
}
__device__ __forceinline__ float dot4x2(uint4 m, uint4 f, float acc) {
  acc = dot2acc(m.x, f.x, acc);
  acc = dot2acc(m.y, f.y, acc);
  acc = dot2acc(m.z, f.z, acc);
  acc = dot2acc(m.w, f.w, acc);
  return acc;
}

// ---------------------------------------------------------------------------
// prep: xfH[b][pix][d] = fp16( s[pix] * xf[b][d][pix] )   (pixel-major, = fm)
//       sc[b][pix]     = s[pix] = T / max(||xf[:,pix]||, 1e-12)
// 32 px/block, 600 blocks; float2 loads + 8B packed stores.
// ---------------------------------------------------------------------------
__global__ __launch_bounds__(256) void prep_kernel(
    const float* __restrict__ xf1, const float* __restrict__ xf2,
    const int* __restrict__ epoch,
    half_t* __restrict__ xf1H, half_t* __restrict__ xf2H,
    float* __restrict__ sc1, float* __restrict__ sc2) {
  __shared__ float tile[32][130];
  __shared__ float qSh[8][32];
  __shared__ float sSh[32];

  const int bi   = blockIdx.x;          // 0..599
  const int img  = bi / 300;
  const int rem  = bi % 300;
  const int b    = rem / 150;
  const int p0   = (rem % 150) * 32;
  const int tid  = threadIdx.x;

  const float* src  = img ? xf2 : xf1;
  half_t* dstH      = img ? xf2H : xf1H;
  float* dstS       = img ? sc2 : sc1;
  const float T     = fminf(1.0f + (float)(*epoch), 50.0f);

  const int dc  = tid >> 4;
  const int pxp = tid & 15;
#pragma unroll
  for (int it = 0; it < 8; ++it) {
    int d = it * 16 + dc;
    float2 v = *reinterpret_cast<const float2*>(
        &src[((size_t)(b * D + d)) * NPIX + p0 + 2 * pxp]);
    tile[2 * pxp][d]     = v.x;
    tile[2 * pxp + 1][d] = v.y;
  }
  __syncthreads();

  {
    const int px = tid & 31;
    const int dg = tid >> 5;
    float s = 0.f;
#pragma unroll
    for (int d = 0; d < 16; ++d) {
      float v = tile[px][dg * 16 + d];
      s += v * v;
    }
    qSh[dg][px] = s;
  }
  __syncthreads();
  if (tid < 32) {
    float s = 0.f;
#pragma unroll
    for (int k = 0; k < 8; ++k) s += qSh[k][tid];
    float sv = T / fmaxf(sqrtf(s), 1e-12f);
    dstS[b * NPIX + p0 + tid] = sv;
    sSh[tid] = sv;
  }
  __syncthreads();

#pragma unroll
  for (int it = 0; it < 4; ++it) {
    int idx = it * 256 + tid;       // quad index, 0..1023
    int lpx = idx >> 5;             // 0..31
    int dq  = (idx & 31) * 4;       // 0..124
    float s = sSh[lpx];
    half2_t h0, h1;
    h0.x = (half_t)(tile[lpx][dq] * s);
    h0.y = (half_t)(tile[lpx][dq + 1] * s);
    h1.x = (half_t)(tile[lpx][dq + 2] * s);
    h1.y = (half_t)(tile[lpx][dq + 3] * s);
    uint2 pack;
    pack.x = __builtin_bit_cast(uint32_t, h0);
    pack.y = __builtin_bit_cast(uint32_t, h1);
    *reinterpret_cast<uint2*>(dstH + ((size_t)(b * NPIX + p0 + lpx)) * D + dq) = pack;
  }
}

// ---------------------------------------------------------------------------
// main: ONE WAVE per (dir, b, n) — 64-thread block, 4096 blocks. Zero
// barriers. Phase 2: depth-4 register param FIFO (LDS read issued 4 iters
// ahead) + depth-2 data pipeline. launch_bounds(64,4) pins VGPR<=128 so the
// grid's 4 waves/SIMD stay resident.
// ---------------------------------------------------------------------------
__global__ __launch_bounds__(64, 4) void line2win_kernel(
    const half_t* __restrict__ xf1H, const half_t* __restrict__ xf2H,
    const float* __restrict__ sc1, const float* __restrict__ sc2,
    const float* __restrict__ F1, const float* __restrict__ F2,
    const float* __restrict__ c1n, const float* __restrict__ c2n,
    float* __restrict__ out) {
  __shared__ __align__(16) half_t featH[D];          // 256 B
  __shared__ float4 sPar[2][128];                    // 4 KB
  __shared__ float corrSh[128];                      // 512 B
  __shared__ float dm[NLAT + 8];                     // 512 B

  const int lane = threadIdx.x;    // 0..63
  // XCD-aware decode: wg w -> XCD w%8 (round-robin heuristic); each (dir,b)
  // combo owns one XCD pair so its two maps (~2.4 MB) L2-fit.
  const int w    = blockIdx.x;          // 0..4095
  const int xcd  = w & 7;
  const int comb = xcd >> 1;            // 0..3 = (dir,b)
  const int dir  = comb >> 1;
  const int b    = comb & 1;
  const int n    = (w >> 3) * 2 + (xcd & 1);   // 0..1023
  const int kix  = b * NKPT + n;

  const half_t* srcH = dir ? xf2H : xf1H;  // descriptor source (pre-scaled fm)
  const float*  ssc  = dir ? sc2 : sc1;    // source scale (to undo)
  const half_t* tgtH = dir ? xf1H : xf2H;  // correlation target (pre-scaled fm)
  const float*  Fm   = (dir ? F2 : F1) + b * 9;
  const float*  cn   = (dir ? c2n : c1n) + kix * 2;

  const float cnx_in = cn[0], cny_in = cn[1];
  const float px = (cnx_in + 1.f) * 319.5f;
  const float py = (cny_in + 1.f) * 239.5f;

  const float la = Fm[0] * px + Fm[1] * py + Fm[2];
  const float lb = Fm[3] * px + Fm[4] * py + Fm[5];
  const float lc = Fm[6] * px + Fm[7] * py + Fm[8];
  const float eps = 1e-8f;
  const bool  use_x = fabsf(lb) >= fabsf(la);
  const float bden  = (fabsf(lb) < eps) ? eps : lb;
  const float aden  = (fabsf(la) < eps) ? eps : la;
  const float rdenom = 1.f / (use_x ? bden : aden);
  const bool  degen = (fabsf(la) < eps) && (fabsf(lb) < eps);

  const size_t tb = (size_t)b * NPIX * D;

  // ---- phase 1a: descriptor (lane holds d-pair 2*lane, 2*lane+1) ----
  float f0 = 0.f, f1 = 0.f;
  {
    float xf = (cnx_in + 1.f) * 39.5f;
    float yf = (cny_in + 1.f) * 29.5f;
    float x0 = floorf(xf), y0 = floorf(yf);
    float wx1 = xf - x0, wx0 = 1.f - wx1;
    float wy1 = yf - y0, wy0 = 1.f - wy1;
#pragma unroll
    for (int cyi = 0; cyi < 2; ++cyi)
#pragma unroll
      for (int cxi = 0; cxi < 2; ++cxi) {
        float xi = x0 + (float)cxi, yi = y0 + (float)cyi;
        bool inb = (xi >= 0.f) && (xi <= (float)(WFm - 1)) &&
                   (yi >= 0.f) && (yi <= (float)(HFm - 1));
        float wgt = (cxi ? wx1 : wx0) * (cyi ? wy1 : wy0);
        if (inb && wgt != 0.f) {
          int p = (int)yi * WFm + (int)xi;
          float coef = wgt / ssc[b * NPIX + p];
          half2_t hv = *reinterpret_cast<const half2_t*>(srcH + tb + (size_t)p * D + 2 * lane);
          f0 += coef * (float)hv.x;
          f1 += coef * (float)hv.y;
        }
      }
  }

  // ---- phase 1b: per-sample line params (lane -> samples lane, lane+64) ----
#pragma unroll
  for (int q = 0; q < 2; ++q) {
    int j = lane + q * 64;
    float tpar = (float)j / 127.0f;
    float xs, ys;
    if (use_x) { xs = tpar * 639.f; ys = -fmaf(la, xs, lc) * rdenom; }
    else       { ys = tpar * 479.f; xs = -fmaf(lb, ys, lc) * rdenom; }
    float xff = fminf(fmaxf(xs * (39.5f / 319.5f), -4.f), 84.f);
    float yff = fminf(fmaxf(ys * (29.5f / 239.5f), -4.f), 64.f);
    float x0f = floorf(xff), y0f = floorf(yff);
    int  x0i = (int)x0f, y0i = (int)y0f;
    float wx1 = xff - x0f, wx0 = 1.f - wx1;
    float wy1 = yff - y0f;
    int  xLow = min(max(x0i, 0), WFm - 2);
    float cL0 = (xLow == x0i) ? wx0 : ((xLow == x0i + 1) ? wx1 : 0.f);
    float cH0 = (xLow + 1 == x0i) ? wx0 : ((xLow + 1 == x0i + 1) ? wx1 : 0.f);
#pragma unroll
    for (int h = 0; h < 2; ++h) {
      int yi = y0i + h;
      bool yin = (yi >= 0) && (yi <= HFm - 1);
      int yc = min(max(yi, 0), HFm - 1);
      float wyh = h ? wy1 : (1.f - wy1);
      float ymul = yin ? wyh : 0.f;
      float4 p4;
      p4.x = __int_as_float(yc * WFm + xLow);
      p4.y = cL0 * ymul;
      p4.z = cH0 * ymul;
      p4.w = 0.f;
      sPar[h][j] = p4;
    }
  }

  // ---- phase 1c: norm (butterfly -> all lanes) + feature store ----
  const float nrm = wsum(f0 * f0 + f1 * f1);
  const float inv = 1.f / fmaxf(sqrtf(nrm), 1e-12f);
  {
    half2_t hv;
    hv.x = (half_t)(f0 * inv);
    hv.y = (half_t)(f1 * inv);
    *reinterpret_cast<half2_t*>(&featH[2 * lane]) = hv;
  }

  const uint4* fH4 = reinterpret_cast<const uint4*>(featH);

  // ---- phase 2: epipolar gather — depth-4 param FIFO + depth-2 data pipe ----
  {
    const int g = lane >> 4;          // sample slot 0..3 (j = it*4+g)
    const int s = lane & 7;
    const int h = (lane >> 3) & 1;
    const uint4 fL0 = fH4[s];
    const uint4 fL1 = fH4[8 + s];

    // param FIFO: pf0..pf3 = params for iters t, t+1, t+2, t+3
    float4 pf0 = sPar[h][g];
    float4 pf1 = sPar[h][4 + g];
    float4 pf2 = sPar[h][8 + g];
    float4 pf3 = sPar[h][12 + g];

    // data stage A (iter t)
    bool actA = (pf0.y != 0.f) || (pf0.z != 0.f);
    uint4 a0{}, a1{}, a2{}, a3{};
    if (actA) {
      const uint4* rp = reinterpret_cast<const uint4*>(
          tgtH + tb + (size_t)__float_as_int(pf0.x) * D);
      a0 = rp[s]; a1 = rp[8 + s]; a2 = rp[16 + s]; a3 = rp[24 + s];
    }
    // data stage B (iter t+1)
    bool actB = (pf1.y != 0.f) || (pf1.z != 0.f);
    uint4 b0{}, b1{}, b2{}, b3{};
    if (actB) {
      const uint4* rp = reinterpret_cast<const uint4*>(
          tgtH + tb + (size_t)__float_as_int(pf1.x) * D);
      b0 = rp[s]; b1 = rp[8 + s]; b2 = rp[16 + s]; b3 = rp[24 + s];
    }

#pragma unroll
    for (int it = 0; it < 32; ++it) {
      // 1) LDS: read param for iter it+4 (resolves over the next 2 iters)
      float4 pfN = {0.f, 0.f, 0.f, 0.f};
      if (it < 28) pfN = sPar[h][(it + 4) * 4 + g];
      // 2) issue data loads for iter it+2 using already-resident pf2
      bool actC = false;
      uint4 c0{}, c1{}, c2{}, c3{};
      if (it < 30) {
        actC = (pf2.y != 0.f) || (pf2.z != 0.f);
        if (actC) {
          const uint4* rp = reinterpret_cast<const uint4*>(
              tgtH + tb + (size_t)__float_as_int(pf2.x) * D);
          c0 = rp[s]; c1 = rp[8 + s]; c2 = rp[16 + s]; c3 = rp[24 + s];
        }
      }
      // 3) compute iter it (stage A, param pf0)
      float acc = 0.f;
      if (actA) {
        float accL = dot4x2(a1, fL1, dot4x2(a0, fL0, 0.f));
        float accH = dot4x2(a3, fL1, dot4x2(a2, fL0, 0.f));
        acc = pf0.y * accL + pf0.z * accH;
      }
      acc += __shfl_xor(acc, 1, 64);
      acc += __shfl_xor(acc, 2, 64);
      acc += __shfl_xor(acc, 4, 64);
      acc += __shfl_xor(acc, 8, 64);   // merge y-halves
      if ((lane & 15) == 0) corrSh[it * 4 + g] = acc;
      // rotate FIFO + stages (all static after unroll)
      pf0 = pf1; pf1 = pf2; pf2 = pf3; pf3 = pfN;
      actA = actB; a0 = b0; a1 = b1; a2 = b2; a3 = b3;
      actB = actC; b0 = c0; b1 = c1; b2 = c2; b3 = c3;
    }
  }

  // ---- phase 3: masked softmax over L=128 (2 samples/lane, butterflies) ----
  float e0, e1, cx0, cy0, cx1, cy1;
  bool v0, v1;
  {
    float lgt0, lgt1;
#pragma unroll
    for (int q = 0; q < 2; ++q) {
      int j = lane + q * 64;
      float tpar = (float)j / 127.0f;
      float xs, ys;
      if (use_x) { xs = tpar * 639.f; ys = -fmaf(la, xs, lc) * rdenom; }
      else       { ys = tpar * 479.f; xs = -fmaf(lb, ys, lc) * rdenom; }
      bool valid = (xs >= 0.f) && (xs <= 639.f) && (ys >= 0.f) && (ys <= 479.f) && !degen;
      float cxj = xs / 319.5f - 1.f;
      float cyj = ys / 239.5f - 1.f;
      float lg = valid ? corrSh[j] : -1e9f;
      if (q == 0) { v0 = valid; cx0 = cxj; cy0 = cyj; lgt0 = lg; }
      else        { v1 = valid; cx1 = cxj; cy1 = cyj; lgt1 = lg; }
    }
    const float mx = wmax(fmaxf(lgt0, lgt1));
    e0 = expf(lgt0 - mx);
    e1 = expf(lgt1 - mx);
  }
  const float sumE = wsum(e0 + e1);
  const float sumX = wsum(e0 * cx0 + e1 * cx1);
  const float sumY = wsum(e0 * cy0 + e1 * cy1);
  const bool  anyv = __ballot(v0 || v1) != 0ull;
  const float meanx = sumX / sumE;
  const float meany = sumY / sumE;
  const float ccx = fminf(fmaxf(meanx, -0.875f), 0.875f);
  const float ccy = fminf(fmaxf(meany, -0.875f), 0.875f);

  if (lane == 0) {
    float* o_coord = out + dir * 4096 + kix * 2;
    o_coord[0] = px;
    o_coord[1] = py;
    float* o_org = out + 16384 + dir * 4096 + kix * 2;
    if (dir == 0) {
      o_org[0] = (meanx + 1.f) * 319.5f;
      o_org[1] = (meany + 1.f) * 239.5f;
    } else {
      o_org[0] = meanx;
      o_org[1] = meany;
    }
    out[28672 + dir * 2048 + kix] = anyv ? 1.f : 0.f;
  }

  // ---- phase 4: window dot-map, 16 lanes/pixel, row-pipelined loads ----
  const float xfc2 = (ccx + 1.f) * 39.5f;
  const float yfc2 = (ccy + 1.f) * 29.5f;
  const int xb = (int)floorf(xfc2 - 4.9375f);   // >= 0
  const int yb = (int)floorf(yfc2 - 3.6875f);   // >= 0
  {
    const int s4 = lane & 15;
    const int pp = lane >> 4;
    const uint4 fw = fH4[s4];
    // row-invariant clamped x offsets and validity
    const int x0p = xb + pp, x1p = xb + 4 + pp, x2p = xb + 8 + pp;
    const bool okx0 = x0p <= WFm - 1, okx1 = x1p <= WFm - 1, okx2 = x2p <= WFm - 1;
    const int pc0 = min(x0p, WFm - 1) - xb;
    const int pc1 = min(x1p, WFm - 1) - xb;
    const int pc2 = min(x2p, WFm - 1) - xb;

    const uint4* rpA = reinterpret_cast<const uint4*>(
        tgtH + tb + (size_t)(min(yb, HFm - 1) * WFm + xb) * D);
    uint4 A0 = rpA[pc0 * 16 + s4];
    uint4 A1 = rpA[pc1 * 16 + s4];
    uint4 A2 = rpA[pc2 * 16 + s4];
#pragma unroll
    for (int row = 0; row < LCY; ++row) {
      uint4 B0{}, B1{}, B2{};
      if (row < LCY - 1) {
        int ycl = min(yb + row + 1, HFm - 1);
        const uint4* rpB = reinterpret_cast<const uint4*>(
            tgtH + tb + (size_t)(ycl * WFm + xb) * D);
        B0 = rpB[pc0 * 16 + s4];
        B1 = rpB[pc1 * 16 + s4];
        B2 = rpB[pc2 * 16 + s4];
      }
      bool yok = (yb + row) <= HFm - 1;
      float d0 = dot4x2(A0, fw, 0.f);
      float d1 = dot4x2(A1, fw, 0.f);
      float d2 = dot4x2(A2, fw, 0.f);
#pragma unroll
      for (int m = 1; m <= 8; m <<= 1) {
        d0 += __shfl_xor(d0, m, 64);
        d1 += __shfl_xor(d1, m, 64);
        d2 += __shfl_xor(d2, m, 64);
      }
      if (s4 == 0) {
        dm[row * LCX + pp]     = (yok && okx0) ? d0 : 0.f;
        dm[row * LCX + 4 + pp] = (yok && okx1) ? d1 : 0.f;
        dm[row * LCX + 8 + pp] = (yok && okx2) ? d2 : 0.f;
      }
      A0 = B0; A1 = B1; A2 = B2;
    }
  }

  // ---- phase 5: 256 window samples (4/lane), softmax + mean + std ----
  const float step = 0.25f / 15.f;
  float t0 = 0.f, t1 = 0.f, t2 = 0.f, t3 = 0.f, t4 = 0.f;
#pragma unroll
  for (int q = 0; q < 4; ++q) {
    int k = lane + q * 64;
    float ox = -0.125f + step * (float)(k & 15);
    float oy = -0.125f + step * (float)(k >> 4);
    float kcx = ccx + ox;
    float kcy = ccy + oy;
    float xfw = xfc2 + ox * 39.5f;
    float yfw = yfc2 + oy * 29.5f;
    float xw0 = floorf(xfw), yw0 = floorf(yfw);
    int ix = (int)xw0 - xb;
    int iy = (int)yw0 - yb;
    float wxx1 = xfw - xw0, wxx0 = 1.f - wxx1;
    float wyy1 = yfw - yw0, wyy0 = 1.f - wyy1;
    int i00 = iy * LCX + ix;
    float c00 = dm[i00], c10 = dm[i00 + 1];
    float c01 = dm[i00 + LCX], c11 = dm[i00 + LCX + 1];
    float corr2 = wxx0 * wyy0 * c00 + wxx1 * wyy0 * c10 +
                  wxx0 * wyy1 * c01 + wxx1 * wyy1 * c11;
    // softmax shift-invariant; logits <= T <= 50 -> expf finite in f32.
    float e2 = expf(corr2);
    t0 += e2;
    t1 += e2 * kcx;
    t2 += e2 * kcy;
    t3 += e2 * kcx * kcx;
    t4 += e2 * kcy * kcy;
  }
  t0 = wsum(t0);
  t1 = wsum(t1);
  t2 = wsum(t2);
  t3 = wsum(t3);
  t4 = wsum(t4);
  if (lane == 0) {
    float mwx = t1 / t0;
    float mwy = t2 / t0;
    float vx  = fmaxf(t3 / t0 - mwx * mwx, 0.f);
    float vy  = fmaxf(t4 / t0 - mwy * mwy, 0.f);
    float stdv = sqrtf(vx + vy + 1e-12f);
    float* o_w = out + 8192 + dir * 4096 + kix * 2;
    o_w[0] = (mwx + 1.f) * 319.5f;
    o_w[1] = (mwy + 1.f) * 239.5f;
    out[24576 + dir * 2048 + kix] = stdv;
  }
}

}  // namespace

extern "C" void kernel_launch(void* const* d_in, const int* in_sizes, int n_in,
                              void* d_out, int out_size, void* d_ws, size_t ws_size,
                              hipStream_t stream) {
  (void)in_sizes; (void)n_in; (void)out_size; (void)ws_size;
  const float* xf1 = (const float*)d_in[0];
  const float* xf2 = (const float*)d_in[1];
  const float* F1  = (const float*)d_in[2];
  const float* F2  = (const float*)d_in[3];
  const float* c1n = (const float*)d_in[4];
  const float* c2n = (const float*)d_in[5];
  const int* epoch = (const int*)d_in[6];

  half_t* xf1H = (half_t*)d_ws;                           // 2*4800*128 halves
  half_t* xf2H = xf1H + (size_t)2 * NPIX * D;             // 2*4800*128 halves
  float*  sc1  = (float*)(xf2H + (size_t)2 * NPIX * D);   // 2*4800 f32
  float*  sc2  = sc1 + 2 * NPIX;                          // 2*4800 f32
  float*  out  = (float*)d_out;

  hipLaunchKernelGGL(prep_kernel, dim3(600), dim3(256), 0, stream,
                     xf1, xf2, epoch, xf1H, xf2H, sc1, sc2);
  hipLaunchKernelGGL(line2win_kernel, dim3(4096), dim3(64), 0, stream,
                     xf1H, xf2H, sc1, sc2, F1, F2, c1n, c2n, out);
}